// Round 5
// baseline (192.325 us; speedup 1.0000x reference)
//
#include <hip/hip_runtime.h>

#define H_IN 4096
#define W_IN 4096
#define KH 15
#define KW 15
#define OH (H_IN - KH + 1)   // 4082
#define OW (W_IN - KW + 1)   // 4082

#define BM 64                // output rows per tile
#define BN 64                // output cols per tile
#define NJ 4                 // j-frags of 16 cols per wave
#define SROWS (BM + KH - 1)  // 78 staged rows
#define SGRAN 16             // 16B granules per LDS row (stride 256 B)
#define ROW_USH (SGRAN * 8)  // 128 ushort per row
#define SCOL4 20             // float4 staged per row (80 cols, 64+15 used)
#define STAGE_N (SROWS * SCOL4)   // 1560 float4 per tile
#define STAGE_IT 7                // ceil(1560/256)
#define BUF_USH (SROWS * ROW_USH) // 9984 ushort = 19968 B per buffer
#define NTX 64               // tiles in x
#define NTY 64               // tiles in y
#define TPB 4                // tiles per block (same column, consecutive y)

typedef __attribute__((ext_vector_type(8))) short short8;   // MFMA A/B frag
typedef __attribute__((ext_vector_type(4))) float f32x4;    // MFMA C/D frag

__device__ __forceinline__ ushort f2bf(float f) {
    union { float f; uint32_t u; } v; v.f = f;
    uint32_t r = (v.u + 0x7FFFu + ((v.u >> 16) & 1u)) >> 16;  // RNE
    return (ushort)r;
}

__global__ __launch_bounds__(256, 4)
void conv2d_mfma_dbuf(const float* __restrict__ X,
                      const float* __restrict__ Wt,
                      const float* __restrict__ Bias,
                      float* __restrict__ Out)
{
    __shared__ ushort s_buf[2][BUF_USH];    // 2 x 19968 B

    const int tid = threadIdx.x;
    const int l   = tid & 63;
    const int w   = tid >> 6;
    const int btx  = blockIdx.x & (NTX - 1);      // tile col
    const int tyg0 = (blockIdx.x >> 6) * TPB;     // first tile row
    const int ox0  = btx * BN;
    const bool xint = (ox0 + SCOL4 * 4 <= W_IN);  // interior in x

    float4 v[STAGE_IT];

    // ---- issue tile-0 global loads FIRST (latency hides under wfrag build) ----
    {
        const int oy0 = tyg0 * BM;
#pragma unroll
        for (int k = 0; k < STAGE_IT; ++k) {
            int f = tid + 256 * k;
            if (f < STAGE_N) {
                int r = f / SCOL4, q = f % SCOL4;
                int gy = min(oy0 + r, H_IN - 1);
                const float* rp = X + (size_t)gy * W_IN;
                int gx = ox0 + q * 4;
                if (xint) {
                    v[k] = *reinterpret_cast<const float4*>(rp + gx);
                } else {
                    v[k].x = rp[min(gx + 0, W_IN - 1)];
                    v[k].y = rp[min(gx + 1, W_IN - 1)];
                    v[k].z = rp[min(gx + 2, W_IN - 1)];
                    v[k].w = rp[min(gx + 3, W_IN - 1)];
                }
            }
        }
    }

    // ---- build banded weight frags in s_buf[1], hoist to regs ----
    // B[k][j] = w[kh][k-j]; lane l holds B[8*(l>>4)+t][l&15]
    for (int idx = tid; idx < KH * 64; idx += 256) {
        int kh = idx >> 6, ll = idx & 63;
        int j = ll & 15, k0 = (ll >> 4) * 8;
        ushort* dst = &s_buf[1][idx * 8];
#pragma unroll
        for (int t = 0; t < 8; ++t) {
            int kw = k0 + t - j;
            float wv = (kw >= 0 && kw < KW) ? Wt[kh * KW + kw] : 0.0f;
            dst[t] = f2bf(wv);
        }
    }
    __syncthreads();
    short8 bfr[KH];
#pragma unroll
    for (int kh = 0; kh < KH; ++kh)
        bfr[kh] = *reinterpret_cast<const short8*>(&s_buf[1][(kh * 64 + l) * 8]);
    __syncthreads();   // frag reads done before buffers are reused

    // ---- write tile 0 into buf 0 (XOR-swizzled granules) ----
#pragma unroll
    for (int k = 0; k < STAGE_IT; ++k) {
        int f = tid + 256 * k;
        if (f < STAGE_N) {
            int r = f / SCOL4, q = f % SCOL4;
            int g = q >> 1, h = q & 1;
            uint2 pk;
            pk.x = (uint32_t)f2bf(v[k].x) | ((uint32_t)f2bf(v[k].y) << 16);
            pk.y = (uint32_t)f2bf(v[k].z) | ((uint32_t)f2bf(v[k].w) << 16);
            *reinterpret_cast<uint2*>(
                &s_buf[0][r * ROW_USH + ((g ^ (r & 7)) * 8) + h * 4]) = pk;
        }
    }
    __syncthreads();

    const int c  = l >> 4;               // A-frag chunk
    const int r0 = w * 16 + (l & 15);    // A-frag local row base
    const float b = Bias[0];
    int cur = 0;

#pragma unroll 1
    for (int t = 0; t < TPB; ++t) {
        // ---- issue next tile's loads (in flight during MFMA) ----
        if (t + 1 < TPB) {
            const int oy0 = (tyg0 + t + 1) * BM;
#pragma unroll
            for (int k = 0; k < STAGE_IT; ++k) {
                int f = tid + 256 * k;
                if (f < STAGE_N) {
                    int r = f / SCOL4, q = f % SCOL4;
                    int gy = min(oy0 + r, H_IN - 1);
                    const float* rp = X + (size_t)gy * W_IN;
                    int gx = ox0 + q * 4;
                    if (xint) {
                        v[k] = *reinterpret_cast<const float4*>(rp + gx);
                    } else {
                        v[k].x = rp[min(gx + 0, W_IN - 1)];
                        v[k].y = rp[min(gx + 1, W_IN - 1)];
                        v[k].z = rp[min(gx + 2, W_IN - 1)];
                        v[k].w = rp[min(gx + 3, W_IN - 1)];
                    }
                }
            }
        }

        // ---- MFMA over buf[cur] ----
        f32x4 acc[NJ];
#pragma unroll
        for (int j = 0; j < NJ; ++j) acc[j] = (f32x4){0.f, 0.f, 0.f, 0.f};

        const ushort* bufp = &s_buf[cur][0];
#pragma unroll
        for (int kh = 0; kh < KH; ++kh) {
            int rr = r0 + kh;
            const ushort* rowb = bufp + rr * ROW_USH;
            int x7 = rr & 7;
#pragma unroll
            for (int j = 0; j < NJ; ++j) {
                int g = 2 * j + c;
                short8 a = *reinterpret_cast<const short8*>(rowb + ((g ^ x7) * 8));
                acc[j] = __builtin_amdgcn_mfma_f32_16x16x32_bf16(a, bfr[kh], acc[j], 0, 0, 0);
            }
        }

        // ---- write next tile into buf[cur^1] (prev readers fenced by last barrier) ----
        if (t + 1 < TPB) {
#pragma unroll
            for (int k = 0; k < STAGE_IT; ++k) {
                int f = tid + 256 * k;
                if (f < STAGE_N) {
                    int r = f / SCOL4, q = f % SCOL4;
                    int g = q >> 1, h = q & 1;
                    uint2 pk;
                    pk.x = (uint32_t)f2bf(v[k].x) | ((uint32_t)f2bf(v[k].y) << 16);
                    pk.y = (uint32_t)f2bf(v[k].z) | ((uint32_t)f2bf(v[k].w) << 16);
                    *reinterpret_cast<uint2*>(
                        &s_buf[cur ^ 1][r * ROW_USH + ((g ^ (r & 7)) * 8) + h * 4]) = pk;
                }
            }
        }

        // ---- store C for tile t ----
        {
            const int oy0 = (tyg0 + t) * BM;
            const int orow0 = oy0 + w * 16 + (l >> 4) * 4;
            const int ocol  = ox0 + (l & 15);
            const bool inter = (ox0 + BN <= OW) && (oy0 + BM <= OH);
            if (inter) {
#pragma unroll
                for (int j = 0; j < NJ; ++j) {
                    float* op = &Out[(size_t)orow0 * OW + ocol + j * 16];
#pragma unroll
                    for (int r = 0; r < 4; ++r)
                        op[(size_t)r * OW] = acc[j][r] + b;
                }
            } else {
#pragma unroll
                for (int j = 0; j < NJ; ++j) {
                    int oc = ocol + j * 16;
                    if (oc < OW) {
#pragma unroll
                        for (int r = 0; r < 4; ++r) {
                            int orow = orow0 + r;
                            if (orow < OH)
                                Out[(size_t)orow * OW + oc] = acc[j][r] + b;
                        }
                    }
                }
            }
        }

        __syncthreads();   // buf[cur^1] fully written; next iter reads it
        cur ^= 1;
    }
}

extern "C" void kernel_launch(void* const* d_in, const int* in_sizes, int n_in,
                              void* d_out, int out_size, void* d_ws, size_t ws_size,
                              hipStream_t stream)
{
    const float* X    = (const float*)d_in[0];
    const float* Wt   = (const float*)d_in[1];
    const float* Bias = (const float*)d_in[2];
    float* Out        = (float*)d_out;

    dim3 grid(NTX * (NTY / TPB));   // 64 * 16 = 1024 blocks, 4 tiles each
    dim3 block(256);
    hipLaunchKernelGGL(conv2d_mfma_dbuf, grid, block, 0, stream, X, Wt, Bias, Out);
}

// Round 6
// 78.009 us; speedup vs baseline: 2.4654x; 2.4654x over previous
//
#include <hip/hip_runtime.h>

#define H_IN 4096
#define W_IN 4096
#define KH 15
#define KW 15
#define OH (H_IN - KH + 1)   // 4082
#define OW (W_IN - KW + 1)   // 4082

#define NJ 4                        // 16-col j-frags per wave
#define WROWS 16                    // output rows per wave-tile
#define WCOLS (16 * NJ)             // 64 output cols per wave-tile
#define SROWS (WROWS + KH - 1)      // 30 staged rows
#define SCH 10                      // 16B chunks per staged row (80 bf16 cols)
#define ROW_USH 96                  // LDS row stride in ushort (192 B = 12 granules)
                                    // A-frag granule class (4*(l&15)+(l>>4))%8:
                                    // exactly 8 lanes/class = conflict-free b128
#define WAVE_USH (SROWS * ROW_USH)  // 2880 ushort = 5760 B per wave
#define NTX 64                      // x tiles
#define NTY 256                     // y tiles
#define TPW 4                       // tiles per wave (consecutive y, same x)

typedef __attribute__((ext_vector_type(8))) short short8;   // MFMA A/B frag
typedef __attribute__((ext_vector_type(4))) float f32x4;    // MFMA C/D frag

__device__ __forceinline__ ushort f2bf(float f) {
    union { float f; uint32_t u; } v; v.f = f;
    uint32_t r = (v.u + 0x7FFFu + ((v.u >> 16) & 1u)) >> 16;  // RNE
    return (ushort)r;
}
__device__ __forceinline__ uint32_t pk2(float a, float b) {
    return (uint32_t)f2bf(a) | ((uint32_t)f2bf(b) << 16);
}

__global__ __launch_bounds__(256, 4)
void conv2d_mfma_wavetile(const float* __restrict__ X,
                          const float* __restrict__ Wt,
                          const float* __restrict__ Bias,
                          float* __restrict__ Out)
{
    __shared__ ushort s[4 * WAVE_USH];   // 23040 B: 4 wave-private tile regions

    const int tid = threadIdx.x;
    const int l = tid & 63;
    const int w = tid >> 6;

    // ---- build banded Toeplitz weight frags (once per block), hoist to regs ----
    // B[k][j] = w[kh][k-j]; lane l holds B[8*(l>>4)+u][l&15], u=0..7
    for (int idx = tid; idx < KH * 64; idx += 256) {
        int kh = idx >> 6, ll = idx & 63;
        int j = ll & 15, k0 = (ll >> 4) * 8;
        ushort* dst = &s[idx * 8];
#pragma unroll
        for (int u = 0; u < 8; ++u) {
            int kw = k0 + u - j;
            dst[u] = f2bf((kw >= 0 && kw < KW) ? Wt[kh * KW + kw] : 0.0f);
        }
    }
    __syncthreads();
    short8 bfr[KH];
#pragma unroll
    for (int kh = 0; kh < KH; ++kh)
        bfr[kh] = *reinterpret_cast<const short8*>(&s[(kh * 64 + l) * 8]);
    __syncthreads();   // last block-wide barrier; below is wave-private

    ushort* const my = &s[w * WAVE_USH];
    const ushort* const abase = my + (l & 15) * ROW_USH + (l >> 4) * 8;
    const float b = Bias[0];

    const int gw  = blockIdx.x * 4 + w;     // global wave id, [0, 4096)
    const int tx  = gw >> 6;                // tile col (constant over t)
    const int ty0 = (gw & 63) * TPW;        // first tile row
    const int ox0 = tx * WCOLS;
    const bool xint = (ox0 + SCH * 8 <= W_IN);

#pragma unroll 1
    for (int t = 0; t < TPW; ++t) {
        const int iy0 = (ty0 + t) * WROWS;

        // ---- wave-private stage: 30 rows x 80 cols fp32 -> bf16 ----
        // all 10 global loads issue together (single vmcnt drain), then 5 b128 writes
#pragma unroll
        for (int it = 0; it < 5; ++it) {
            int idx = it * 64 + l;
            if (idx < SROWS * SCH) {
                int r = idx / SCH, q = idx % SCH;
                int gy = min(iy0 + r, H_IN - 1);
                const float* rp = X + (size_t)gy * W_IN;
                int gx = ox0 + q * 8;
                float4 va, vb;
                if (xint) {
                    va = *reinterpret_cast<const float4*>(rp + gx);
                    vb = *reinterpret_cast<const float4*>(rp + gx + 4);
                } else {
                    va.x = rp[min(gx + 0, W_IN - 1)];
                    va.y = rp[min(gx + 1, W_IN - 1)];
                    va.z = rp[min(gx + 2, W_IN - 1)];
                    va.w = rp[min(gx + 3, W_IN - 1)];
                    vb.x = rp[min(gx + 4, W_IN - 1)];
                    vb.y = rp[min(gx + 5, W_IN - 1)];
                    vb.z = rp[min(gx + 6, W_IN - 1)];
                    vb.w = rp[min(gx + 7, W_IN - 1)];
                }
                uint4 pk;
                pk.x = pk2(va.x, va.y);
                pk.y = pk2(va.z, va.w);
                pk.z = pk2(vb.x, vb.y);
                pk.w = pk2(vb.z, vb.w);
                *reinterpret_cast<uint4*>(&my[r * ROW_USH + q * 8]) = pk;
            }
        }
        // no barrier: wave-private region; DS ops are in-order per wave and the
        // compiler orders reads/writes through the shared array conservatively.

        // ---- compute: 15 kh x 4 j MFMAs, A-frags via static-offset b128 ----
        f32x4 acc[NJ];
#pragma unroll
        for (int j = 0; j < NJ; ++j) acc[j] = (f32x4){0.f, 0.f, 0.f, 0.f};

#pragma unroll
        for (int kh = 0; kh < KH; ++kh) {
#pragma unroll
            for (int j = 0; j < NJ; ++j) {
                short8 a = *reinterpret_cast<const short8*>(abase + kh * ROW_USH + j * 16);
                acc[j] = __builtin_amdgcn_mfma_f32_16x16x32_bf16(a, bfr[kh], acc[j], 0, 0, 0);
            }
        }

        // ---- store: C/D layout col=lane&15, row=(lane>>4)*4+r ----
        const int orow0 = iy0 + (l >> 4) * 4;
        const int ocol  = ox0 + (l & 15);
        if (iy0 + WROWS <= OH && ox0 + WCOLS <= OW) {
            float* op0 = &Out[(size_t)orow0 * OW + ocol];
#pragma unroll
            for (int j = 0; j < NJ; ++j) {
#pragma unroll
                for (int r = 0; r < 4; ++r)
                    op0[(size_t)r * OW + j * 16] = acc[j][r] + b;
            }
        } else {
#pragma unroll
            for (int j = 0; j < NJ; ++j) {
                int oc = ocol + j * 16;
                if (oc < OW) {
#pragma unroll
                    for (int r = 0; r < 4; ++r) {
                        int orow = orow0 + r;
                        if (orow < OH)
                            Out[(size_t)orow * OW + oc] = acc[j][r] + b;
                    }
                }
            }
        }
    }
}

extern "C" void kernel_launch(void* const* d_in, const int* in_sizes, int n_in,
                              void* d_out, int out_size, void* d_ws, size_t ws_size,
                              hipStream_t stream)
{
    const float* X    = (const float*)d_in[0];
    const float* Wt   = (const float*)d_in[1];
    const float* Bias = (const float*)d_in[2];
    float* Out        = (float*)d_out;

    // 16384 wave-tiles / (4 waves/block * 4 tiles/wave) = 1024 persistent blocks
    dim3 grid(NTX * NTY / (4 * TPW));
    dim3 block(256);
    hipLaunchKernelGGL(conv2d_mfma_wavetile, grid, block, 0, stream, X, Wt, Bias, Out);
}